// Round 1
// baseline (156.274 us; speedup 1.0000x reference)
//
#include <hip/hip_runtime.h>
#include <math.h>

#define H 1024
#define B 64
#define L 2048

// ---------------------------------------------------------------------------
// Kernel 1: u[b,h] = sum_g hidden[b,g] * W[g,h]   (u = hidden @ W)
// grid (B, 4), block 256. Block (b, hc) computes u[b, hc*256 .. hc*256+255].
// hidden row staged in LDS (broadcast reads are conflict-free); W reads are
// 1 KB contiguous per block per iteration; W (4 MB) stays L2/L3 resident.
// ---------------------------------------------------------------------------
__global__ __launch_bounds__(256) void compute_u_kernel(
        const float* __restrict__ hidden,
        const float* __restrict__ W,
        float* __restrict__ u) {
    __shared__ float hid[H];
    const int b   = blockIdx.x;
    const int hc  = blockIdx.y;
    const int tid = threadIdx.x;

    for (int i = tid; i < H; i += 256) hid[i] = hidden[b * H + i];
    __syncthreads();

    const int h = hc * 256 + tid;
    float acc = 0.f;
#pragma unroll 8
    for (int g = 0; g < H; ++g) {
        acc = fmaf(hid[g], W[g * H + h], acc);
    }
    u[b * H + h] = acc;
}

// ---------------------------------------------------------------------------
// Kernel 2: scores[b,l] = dot(enc[l,b,:], u[b,:])
// One wave per (l,b) pair. p = l*B + b is the contiguous dimension of enc,
// so consecutive waves stream consecutive 4 KB chunks (perfect coalescing).
// This is the 512 MB HBM-bound pass — the roofline.
// Writes scores into d_out[b*L + l] (softmax'd in place by kernel 3).
// ---------------------------------------------------------------------------
__global__ __launch_bounds__(256) void scores_kernel(
        const float4* __restrict__ enc4,
        const float4* __restrict__ u4,
        float* __restrict__ scores) {
    const int wave = threadIdx.x >> 6;
    const int lane = threadIdx.x & 63;
    const int p    = blockIdx.x * 4 + wave;   // pair index = l*B + b
    const int b    = p & (B - 1);

    const float4* __restrict__ e  = enc4 + (size_t)p * (H / 4);
    const float4* __restrict__ uu = u4 + (size_t)b * (H / 4);

    float acc = 0.f;
#pragma unroll
    for (int it = 0; it < 4; ++it) {
        const int idx = it * 64 + lane;
        const float4 ev = e[idx];
        const float4 uv = uu[idx];
        acc = fmaf(ev.x, uv.x, acc);
        acc = fmaf(ev.y, uv.y, acc);
        acc = fmaf(ev.z, uv.z, acc);
        acc = fmaf(ev.w, uv.w, acc);
    }

#pragma unroll
    for (int off = 32; off; off >>= 1) acc += __shfl_down(acc, off);

    if (lane == 0) {
        const int l = p >> 6;                 // p / B
        scores[(size_t)b * L + l] = acc;
    }
}

// ---------------------------------------------------------------------------
// Kernel 3: in-place row softmax over d_out, one block per b.
// 256 threads x 8 elements (2 float4 each). Wave shuffle reduce + LDS combine.
// ---------------------------------------------------------------------------
__global__ __launch_bounds__(256) void softmax_kernel(float* __restrict__ out) {
    __shared__ float red[8];
    const int b    = blockIdx.x;
    const int tid  = threadIdx.x;
    const int wave = tid >> 6;
    const int lane = tid & 63;

    float4* __restrict__ r4 = (float4*)(out + (size_t)b * L);
    float4 a0 = r4[tid];
    float4 a1 = r4[256 + tid];

    float m = fmaxf(fmaxf(fmaxf(a0.x, a0.y), fmaxf(a0.z, a0.w)),
                    fmaxf(fmaxf(a1.x, a1.y), fmaxf(a1.z, a1.w)));
#pragma unroll
    for (int off = 32; off; off >>= 1) m = fmaxf(m, __shfl_down(m, off));
    if (lane == 0) red[wave] = m;
    __syncthreads();
    m = fmaxf(fmaxf(red[0], red[1]), fmaxf(red[2], red[3]));

    float e0 = expf(a0.x - m), e1 = expf(a0.y - m);
    float e2 = expf(a0.z - m), e3 = expf(a0.w - m);
    float e4 = expf(a1.x - m), e5 = expf(a1.y - m);
    float e6 = expf(a1.z - m), e7 = expf(a1.w - m);

    float s = ((e0 + e1) + (e2 + e3)) + ((e4 + e5) + (e6 + e7));
#pragma unroll
    for (int off = 32; off; off >>= 1) s += __shfl_down(s, off);
    if (lane == 0) red[4 + wave] = s;
    __syncthreads();
    s = (red[4] + red[5]) + (red[6] + red[7]);

    const float inv = 1.f / s;
    a0.x = e0 * inv; a0.y = e1 * inv; a0.z = e2 * inv; a0.w = e3 * inv;
    a1.x = e4 * inv; a1.y = e5 * inv; a1.z = e6 * inv; a1.w = e7 * inv;
    r4[tid]       = a0;
    r4[256 + tid] = a1;
}

extern "C" void kernel_launch(void* const* d_in, const int* in_sizes, int n_in,
                              void* d_out, int out_size, void* d_ws, size_t ws_size,
                              hipStream_t stream) {
    const float* hidden = (const float*)d_in[0];  // [B, H]
    const float* enc    = (const float*)d_in[1];  // [L, B, H]
    const float* W      = (const float*)d_in[2];  // [H, H]
    // d_in[3] (bias) is provably irrelevant: it adds a per-b constant to
    // scores[b,:], which softmax over l cancels exactly.

    float* u   = (float*)d_ws;                    // [B, H] = 256 KB scratch
    float* out = (float*)d_out;                   // [B, 1, L] fp32

    // 1) u = hidden @ W
    compute_u_kernel<<<dim3(B, 4), 256, 0, stream>>>(hidden, W, u);

    // 2) scores[b,l] = dot(enc[l,b,:], u[b,:])  -> written into d_out
    scores_kernel<<<(L * B) / 4, 256, 0, stream>>>(
        (const float4*)enc, (const float4*)u, out);

    // 3) softmax over l, in place
    softmax_kernel<<<B, 256, 0, stream>>>(out);
}

// Round 2
// 122.333 us; speedup vs baseline: 1.2774x; 1.2774x over previous
//
#include <hip/hip_runtime.h>
#include <math.h>

#define H 1024
#define B 64
#define L 2048

#define GC 16   // g-chunks (64 g each)
#define HC 4    // h-chunks (256 h each)
#define BG 4    // b-groups (16 b each)

// ---------------------------------------------------------------------------
// Kernel 1a: partial[b][gc][h] = sum_{g in chunk gc} hidden[b,g] * W[g,h]
// grid (GC, HC, BG), block 256. Each thread owns one h and accumulates 16 b's
// in registers. hidden reads are wave-uniform -> scalar loads (SGPR operand
// feeds v_fmac directly). W is read 4x logically (16 MB, L2-cached; 4 MB HBM).
// FMA-bound: 1024 FMA/thread ~ 2048 cyc.
// ---------------------------------------------------------------------------
__global__ __launch_bounds__(256) void u_partial_kernel(
        const float* __restrict__ hidden,
        const float* __restrict__ W,
        float* __restrict__ partial) {
    const int h  = blockIdx.y * 256 + threadIdx.x;
    const int g0 = blockIdx.x * 64;
    const int b0 = blockIdx.z * 16;

    float acc[16];
#pragma unroll
    for (int bb = 0; bb < 16; ++bb) acc[bb] = 0.f;

#pragma unroll 4
    for (int gg = 0; gg < 64; ++gg) {
        const int g = g0 + gg;
        const float w = W[(size_t)g * H + h];
#pragma unroll
        for (int bb = 0; bb < 16; ++bb) {
            acc[bb] = fmaf(hidden[(b0 + bb) * H + g], w, acc[bb]);
        }
    }

#pragma unroll
    for (int bb = 0; bb < 16; ++bb) {
        partial[((size_t)(b0 + bb) * GC + blockIdx.x) * H + h] = acc[bb];
    }
}

// ---------------------------------------------------------------------------
// Kernel 1b: u[b][h] = sum_gc partial[b][gc][h]. 65536 threads, 4 MB read.
// ---------------------------------------------------------------------------
__global__ __launch_bounds__(256) void u_reduce_kernel(
        const float* __restrict__ partial,
        float* __restrict__ u) {
    const int idx = blockIdx.x * 256 + threadIdx.x;   // b*H + h
    const int b = idx >> 10;
    const int h = idx & (H - 1);
    float s = 0.f;
#pragma unroll
    for (int gc = 0; gc < GC; ++gc) {
        s += partial[((size_t)b * GC + gc) * H + h];
    }
    u[idx] = s;
}

// ---------------------------------------------------------------------------
// Kernel 2: scores[b,l] = dot(enc[l,b,:], u[b,:]).
// One wave handles ITER=8 consecutive l's for a FIXED b: u row (4 KB) cached
// in 16 VGPRs, so the only streaming traffic is enc (512 MB, the roofline).
// enc reads: 4x float4 per l, each a contiguous 1 KB wave transaction.
// ---------------------------------------------------------------------------
#define ITER 8
__global__ __launch_bounds__(256) void scores_kernel(
        const float4* __restrict__ enc4,
        const float4* __restrict__ u4,
        float* __restrict__ scores) {
    const int wave = threadIdx.x >> 6;
    const int lane = threadIdx.x & 63;
    const int gw   = blockIdx.x * 4 + wave;        // [0, B*L/ITER)
    const int b    = gw & (B - 1);
    const int l0   = (gw >> 6) * ITER;

    const float4* __restrict__ uu = u4 + (size_t)b * (H / 4);
    const float4 uv0 = uu[lane];
    const float4 uv1 = uu[64 + lane];
    const float4 uv2 = uu[128 + lane];
    const float4 uv3 = uu[192 + lane];

    const float4* __restrict__ e = enc4 + ((size_t)l0 * B + b) * (H / 4);

    float acc[ITER];
#pragma unroll
    for (int i = 0; i < ITER; ++i) {
        const float4* __restrict__ ei = e + (size_t)i * B * (H / 4);
        const float4 e0 = ei[lane];
        const float4 e1 = ei[64 + lane];
        const float4 e2 = ei[128 + lane];
        const float4 e3 = ei[192 + lane];
        float a = e0.x * uv0.x;
        a = fmaf(e0.y, uv0.y, a);
        a = fmaf(e0.z, uv0.z, a);
        a = fmaf(e0.w, uv0.w, a);
        a = fmaf(e1.x, uv1.x, a);
        a = fmaf(e1.y, uv1.y, a);
        a = fmaf(e1.z, uv1.z, a);
        a = fmaf(e1.w, uv1.w, a);
        a = fmaf(e2.x, uv2.x, a);
        a = fmaf(e2.y, uv2.y, a);
        a = fmaf(e2.z, uv2.z, a);
        a = fmaf(e2.w, uv2.w, a);
        a = fmaf(e3.x, uv3.x, a);
        a = fmaf(e3.y, uv3.y, a);
        a = fmaf(e3.z, uv3.z, a);
        a = fmaf(e3.w, uv3.w, a);
        acc[i] = a;
    }

#pragma unroll
    for (int i = 0; i < ITER; ++i) {
#pragma unroll
        for (int off = 32; off; off >>= 1) acc[i] += __shfl_down(acc[i], off);
    }

    if (lane == 0) {
        float4 s0 = make_float4(acc[0], acc[1], acc[2], acc[3]);
        float4 s1 = make_float4(acc[4], acc[5], acc[6], acc[7]);
        float4* dst = (float4*)(scores + (size_t)b * L + l0);
        dst[0] = s0;
        dst[1] = s1;
    }
}

// ---------------------------------------------------------------------------
// Kernel 3: in-place row softmax, one block (512 threads) per b, 1 float4/thr.
// ---------------------------------------------------------------------------
__global__ __launch_bounds__(512) void softmax_kernel(float* __restrict__ out) {
    __shared__ float redm[8];
    __shared__ float reds[8];
    const int b    = blockIdx.x;
    const int tid  = threadIdx.x;
    const int wave = tid >> 6;
    const int lane = tid & 63;

    float4* __restrict__ r4 = (float4*)(out + (size_t)b * L);
    float4 a = r4[tid];

    float m = fmaxf(fmaxf(a.x, a.y), fmaxf(a.z, a.w));
#pragma unroll
    for (int off = 32; off; off >>= 1) m = fmaxf(m, __shfl_down(m, off));
    if (lane == 0) redm[wave] = m;
    __syncthreads();
    m = fmaxf(fmaxf(fmaxf(redm[0], redm[1]), fmaxf(redm[2], redm[3])),
              fmaxf(fmaxf(redm[4], redm[5]), fmaxf(redm[6], redm[7])));

    float e0 = expf(a.x - m), e1 = expf(a.y - m);
    float e2 = expf(a.z - m), e3 = expf(a.w - m);

    float s = (e0 + e1) + (e2 + e3);
#pragma unroll
    for (int off = 32; off; off >>= 1) s += __shfl_down(s, off);
    if (lane == 0) reds[wave] = s;
    __syncthreads();
    s = ((reds[0] + reds[1]) + (reds[2] + reds[3])) +
        ((reds[4] + reds[5]) + (reds[6] + reds[7]));

    const float inv = 1.f / s;
    a.x = e0 * inv; a.y = e1 * inv; a.z = e2 * inv; a.w = e3 * inv;
    r4[tid] = a;
}

extern "C" void kernel_launch(void* const* d_in, const int* in_sizes, int n_in,
                              void* d_out, int out_size, void* d_ws, size_t ws_size,
                              hipStream_t stream) {
    const float* hidden = (const float*)d_in[0];  // [B, H]
    const float* enc    = (const float*)d_in[1];  // [L, B, H]
    const float* W      = (const float*)d_in[2];  // [H, H]
    // d_in[3] (bias) cancels in the softmax over l — provably irrelevant.

    float* u       = (float*)d_ws;                        // [B, H]      256 KB
    float* partial = (float*)d_ws + (size_t)B * H;        // [B, GC, H]  4 MB
    float* out     = (float*)d_out;                       // [B, 1, L]   fp32

    // 1) u = hidden @ W (partial + reduce)
    u_partial_kernel<<<dim3(GC, HC, BG), 256, 0, stream>>>(hidden, W, partial);
    u_reduce_kernel<<<(B * H) / 256, 256, 0, stream>>>(partial, u);

    // 2) scores[b,l] = dot(enc[l,b,:], u[b,:]) -> d_out
    scores_kernel<<<(B * L / ITER) / 4, 256, 0, stream>>>(
        (const float4*)enc, (const float4*)u, out);

    // 3) softmax over l, in place
    softmax_kernel<<<B, 512, 0, stream>>>(out);
}